// Round 3
// baseline (745.158 us; speedup 1.0000x reference)
//
#include <hip/hip_runtime.h>
#include <math.h>

#define EPSV   1e-5f

typedef __attribute__((ext_vector_type(8))) short bf16x8;
typedef __attribute__((ext_vector_type(4))) float f32x4;

__device__ __forceinline__ short f2bf(float f){
    unsigned u = __float_as_uint(f);
    u += 0x7fffu + ((u >> 16) & 1u);
    return (short)(u >> 16);
}
__device__ __forceinline__ f32x4 mfma16(bf16x8 a, bf16x8 b, f32x4 c){
    return __builtin_amdgcn_mfma_f32_16x16x32_bf16(a, b, c, 0, 0, 0);
}
// swizzled LDS fragment load: row-major bf16 tile, rowBytes per row, XOR swizzle
__device__ __forceinline__ bf16x8 ldfrag(const short* base, int row, int kbyte, int rowBytes){
    int byte = row * rowBytes + kbyte;
    byte ^= (row & 7) << 4;
    return *(const bf16x8*)((const char*)base + byte);
}
__device__ __forceinline__ bf16x8 ldfragG(const short* base, int row, int kbyte, int rowBytes){
    return *(const bf16x8*)((const char*)base + (size_t)row * rowBytes + kbyte);
}
__device__ __forceinline__ void stswz(short* base, int row, int col, int rowBytes, short v){
    int byte = row * rowBytes + col * 2;
    byte ^= (row & 7) << 4;
    *(short*)((char*)base + byte) = v;
}

// ---------------------------------------------------------------------------
__global__ __launch_bounds__(256) void cvt_bf16(const float* __restrict__ src,
                                                short* __restrict__ dst, int n)
{
    int i = (blockIdx.x * 256 + threadIdx.x) * 4;
    if (i + 3 < n) {
        float4 v = *(const float4*)(src + i);
        short4 s;
        s.x = f2bf(v.x); s.y = f2bf(v.y); s.z = f2bf(v.z); s.w = f2bf(v.w);
        *(short4*)(dst + i) = s;
    }
}

// ---------------------------------------------------------------------------
// GCN branch (unchanged)
// ---------------------------------------------------------------------------
__global__ __launch_bounds__(256) void gcn_main(
    const float* __restrict__ x,
    const float* __restrict__ Wg1, const float* __restrict__ bg1,
    const float* __restrict__ Wg2, const float* __restrict__ bg2,
    float* __restrict__ xgcn)
{
    __shared__ float xg[2][9];
    __shared__ float h1[2][64];
    int tid = threadIdx.x;
    int ri = tid >> 7;
    int tr = tid & 127;
    int row = blockIdx.x * 2 + ri;

    if (tr < 9) {
        const float* xp = x + (row * 9 + tr) * 7;
        float s = 0.f;
        #pragma unroll
        for (int f = 0; f < 7; ++f) s += xp[f];
        xg[ri][tr] = s * (1.f / 7.f);
    }
    __syncthreads();
    if (tr < 64) {
        float acc = bg1[tr];
        #pragma unroll
        for (int j = 0; j < 9; ++j) acc += xg[ri][j] * Wg1[j * 64 + tr];
        h1[ri][tr] = fmaxf(acc, 0.f);
    }
    __syncthreads();
    {
        float acc = bg2[tr];
        #pragma unroll 8
        for (int c = 0; c < 64; ++c) acc += h1[ri][c] * Wg2[c * 128 + tr];
        xgcn[row * 128 + tr] = fmaxf(acc, 0.f);
    }
}

__global__ void gcn_small(
    const float* __restrict__ x,
    const float* __restrict__ Wg1, const float* __restrict__ bg1,
    const float* __restrict__ Wg2, const float* __restrict__ bg2,
    float* __restrict__ xgcn)
{
    __shared__ float xgm[9];
    __shared__ float h1[64];
    int tid = threadIdx.x;
    if (tid < 9) {
        float s = 0.f;
        for (int r = 0; r < 9; ++r) {
            const float* xp = x + (r * 9 + tid) * 7;
            #pragma unroll
            for (int f = 0; f < 7; ++f) s += xp[f];
        }
        xgm[tid] = s * (1.f / 63.f);
    }
    __syncthreads();
    if (tid < 64) {
        float acc = bg1[tid];
        #pragma unroll
        for (int j = 0; j < 9; ++j) acc += xgm[j] * Wg1[j * 64 + tid];
        h1[tid] = fmaxf(acc, 0.f);
    }
    __syncthreads();
    {
        float acc = bg2[tid];
        #pragma unroll 8
        for (int c = 0; c < 64; ++c) acc += h1[c] * Wg2[c * 128 + tid];
        float v = fmaxf(acc, 0.f);
        for (int r = 0; r < 9; ++r) xgcn[r * 128 + tid] = v;
    }
}

// ---------------------------------------------------------------------------
// Conv branch (unchanged)
// ---------------------------------------------------------------------------
__global__ __launch_bounds__(256) void conv_branch(
    const float* __restrict__ x,
    const float* __restrict__ w1, const float* __restrict__ cb1,
    const float* __restrict__ w2, const float* __restrict__ cb2,
    const float* __restrict__ bng, const float* __restrict__ bnb,
    const float* __restrict__ bnm, const float* __restrict__ bnv,
    float* __restrict__ sbuf)
{
    __shared__ float xm[7 * 40];
    __shared__ float w1s[64 * 35];
    __shared__ float o1[64 * 38];
    int tid = threadIdx.x;
    int b = blockIdx.x;

    for (int idx = tid; idx < 7 * 40; idx += 256) xm[idx] = 0.f;
    for (int idx = tid; idx < 64 * 38; idx += 256) o1[idx] = 0.f;
    for (int idx = tid; idx < 2240; idx += 256) w1s[idx] = w1[idx];
    __syncthreads();

    const float* xb = x + (size_t)b * 2268;
    for (int idx = tid; idx < 252; idx += 256) {
        int f = idx / 36, l = idx - f * 36;
        float s = 0.f;
        #pragma unroll
        for (int n = 0; n < 9; ++n) s += xb[n * 252 + idx];
        xm[f * 40 + l + 2] = s * (1.f / 9.f);
    }
    __syncthreads();

    {
        int o = tid & 63, lh = tid >> 6;
        int l0 = lh * 9;
        float acc[9];
        float bias = cb1[o];
        #pragma unroll
        for (int r = 0; r < 9; ++r) acc[r] = bias;
        #pragma unroll
        for (int i = 0; i < 7; ++i) {
            #pragma unroll
            for (int k = 0; k < 5; ++k) {
                float w = w1s[o * 35 + i * 5 + k];
                const float* xrow = &xm[i * 40 + l0 + k];
                #pragma unroll
                for (int r = 0; r < 9; ++r) acc[r] += w * xrow[r];
            }
        }
        #pragma unroll
        for (int r = 0; r < 9; ++r) o1[o * 38 + l0 + r + 1] = acc[r];
    }
    __syncthreads();

    {
        int c = tid & 127, lh = tid >> 7;
        int l0 = lh * 18;
        float acc[18];
        #pragma unroll
        for (int r = 0; r < 18; ++r) acc[r] = 0.f;
        const float* w2c = w2 + c * 192;
        for (int i = 0; i < 64; ++i) {
            float wa = w2c[i * 3 + 0], wb = w2c[i * 3 + 1], wc = w2c[i * 3 + 2];
            const float* orow = &o1[i * 38 + l0];
            #pragma unroll
            for (int r = 0; r < 18; ++r)
                acc[r] += wa * orow[r] + wb * orow[r + 1] + wc * orow[r + 2];
        }
        float scale = bng[c] * rsqrtf(bnv[c] + EPSV);
        float shift = bnb[c] - bnm[c] * scale;
        float bias  = cb2[c];
        float* sb = sbuf + ((size_t)b * 36 + l0) * 128 + c;
        #pragma unroll
        for (int r = 0; r < 18; ++r)
            sb[r * 128] = (acc[r] + bias) * scale + shift;
    }
}

// ---------------------------------------------------------------------------
// Fused transformer layer v2: barrier-free chunk-parallel FFN, parallel
// softmax/LN. One batch element per block; 256 threads = 4 waves.
// ---------------------------------------------------------------------------
__global__ __launch_bounds__(256, 2) void xformer_mfma(
    float* __restrict__ sbuf,
    const short* __restrict__ ipwb, const float* __restrict__ ipb,
    const short* __restrict__ opwb, const float* __restrict__ opb,
    const float* __restrict__ l1g, const float* __restrict__ l1b,
    const float* __restrict__ l2g, const float* __restrict__ l2b,
    const short* __restrict__ fw1b, const float* __restrict__ fb1,
    const short* __restrict__ fw2b, const float* __restrict__ fb2)
{
    __shared__ float Sf[36 * 129];                               // 18576 B
    __shared__ short Sb[48 * 128] __attribute__((aligned(16)));  // 12288 B
    __shared__ char  U[38912]     __attribute__((aligned(16)));  // union
    __shared__ float scf[36 * 40];                               // 5760 B
    // attention views of U:
    short* Qb = (short*)U;               // 48x64   (6144)
    short* Kb = (short*)(U + 6144);      // 48x64   (6144)
    short* Vt = (short*)(U + 12288);     // 64x64   (8192)  [d][seq]
    short* Pb = (short*)(U + 20480);     // 48x64   (6144)
    short* Hb = (short*)(U + 26624);     // 48x128  (12288)
    // FFN view of U (attention data dead by then):
    const int tid  = threadIdx.x;
    const int wid  = tid >> 6;
    const int lane = tid & 63;
    const int lr   = lane & 15;
    const int lg   = lane >> 4;
    const int kbse = lg * 16;
    short* scr = (short*)(U + wid * 6144);   // per-wave 48x64 scratch

    float* sg = sbuf + (size_t)blockIdx.x * 4608;
    const f32x4 fzero = {0.f, 0.f, 0.f, 0.f};

    // ---- init ----
    for (int idx = tid; idx < 4608; idx += 256) {
        int r = idx >> 7, c = idx & 127;
        float v = sg[idx];
        Sf[r * 129 + c] = v;
        stswz(Sb, r, c, 256, f2bf(v));
    }
    for (int idx = tid; idx < 1536; idx += 256)                 // Sb pad rows
        stswz(Sb, 36 + (idx >> 7), idx & 127, 256, 0);
    for (int idx = tid; idx < 1024; idx += 256)                 // Vt seq 48..63
        stswz(Vt, idx >> 4, 48 + (idx & 15), 128, 0);
    for (int idx = tid; idx < 768; idx += 256)                  // Pb pad rows
        stswz(Pb, 36 + (idx >> 6), idx & 63, 128, 0);
    __syncthreads();

    // ================= attention =================
    for (int h = 0; h < 2; ++h) {
        {   // q,k,v projections
            f32x4 acc[3][3];
            #pragma unroll
            for (int a = 0; a < 3; ++a)
                #pragma unroll
                for (int m = 0; m < 3; ++m) acc[a][m] = fzero;
            const int wrow0 = h * 64 + wid * 16 + lr;
            #pragma unroll
            for (int ks = 0; ks < 4; ++ks) {
                bf16x8 a0 = ldfrag(Sb,      lr, ks * 64 + kbse, 256);
                bf16x8 a1 = ldfrag(Sb, 16 + lr, ks * 64 + kbse, 256);
                bf16x8 a2 = ldfrag(Sb, 32 + lr, ks * 64 + kbse, 256);
                #pragma unroll
                for (int mat = 0; mat < 3; ++mat) {
                    bf16x8 bf = ldfragG(ipwb, mat * 128 + wrow0, ks * 64 + kbse, 256);
                    acc[mat][0] = mfma16(a0, bf, acc[mat][0]);
                    acc[mat][1] = mfma16(a1, bf, acc[mat][1]);
                    acc[mat][2] = mfma16(a2, bf, acc[mat][2]);
                }
            }
            int col = wid * 16 + lr;
            #pragma unroll
            for (int mat = 0; mat < 3; ++mat) {
                float bias = ipb[mat * 128 + h * 64 + col];
                #pragma unroll
                for (int mt = 0; mt < 3; ++mt) {
                    f32x4 c4 = acc[mat][mt];
                    if (mat == 0) {
                        #pragma unroll
                        for (int j = 0; j < 4; ++j)
                            stswz(Qb, mt * 16 + lg * 4 + j, col, 128, f2bf(c4[j] + bias));
                    } else if (mat == 1) {
                        #pragma unroll
                        for (int j = 0; j < 4; ++j)
                            stswz(Kb, mt * 16 + lg * 4 + j, col, 128, f2bf(c4[j] + bias));
                    } else {
                        short4 s4;
                        s4.x = f2bf(c4[0] + bias); s4.y = f2bf(c4[1] + bias);
                        s4.z = f2bf(c4[2] + bias); s4.w = f2bf(c4[3] + bias);
                        int byte = col * 128 + (mt * 16 + lg * 4) * 2;
                        byte ^= (col & 7) << 4;
                        *(short4*)((char*)Vt + byte) = s4;
                    }
                }
            }
        }
        __syncthreads();

        // ---- scores ----
        for (int t = wid; t < 9; t += 4) {
            int mt = t / 3, nt = t - mt * 3;
            f32x4 acc = fzero;
            #pragma unroll
            for (int ks = 0; ks < 2; ++ks) {
                bf16x8 a = ldfrag(Qb, mt * 16 + lr, ks * 64 + kbse, 128);
                bf16x8 b = ldfrag(Kb, nt * 16 + lr, ks * 64 + kbse, 128);
                acc = mfma16(a, b, acc);
            }
            int col = nt * 16 + lr;
            if (col < 36) {
                #pragma unroll
                for (int j = 0; j < 4; ++j) {
                    int r = mt * 16 + lg * 4 + j;
                    if (r < 36) scf[r * 40 + col] = acc[j] * 0.125f;
                }
            }
        }
        __syncthreads();

        // ---- softmax: 4 lanes per row ----
        {
            int g = tid >> 2, e = tid & 3;
            if (g < 36) {
                float v[9];
                float mx = -1e30f;
                #pragma unroll
                for (int i = 0; i < 9; ++i) { v[i] = scf[g * 40 + e * 9 + i]; mx = fmaxf(mx, v[i]); }
                mx = fmaxf(mx, __shfl_xor(mx, 1));
                mx = fmaxf(mx, __shfl_xor(mx, 2));
                float ssum = 0.f;
                #pragma unroll
                for (int i = 0; i < 9; ++i) { v[i] = __expf(v[i] - mx); ssum += v[i]; }
                ssum += __shfl_xor(ssum, 1);
                ssum += __shfl_xor(ssum, 2);
                float inv = 1.f / ssum;
                #pragma unroll
                for (int i = 0; i < 9; ++i)
                    stswz(Pb, g, e * 9 + i, 128, f2bf(v[i] * inv));
                #pragma unroll
                for (int i = 0; i < 7; ++i)                      // zero cols 36..63
                    stswz(Pb, g, 36 + e * 7 + i, 128, 0);
            }
        }
        __syncthreads();

        // ---- o = P @ V ----
        {
            f32x4 oacc[3] = {fzero, fzero, fzero};
            #pragma unroll
            for (int ks = 0; ks < 2; ++ks) {
                bf16x8 b = ldfrag(Vt, wid * 16 + lr, ks * 64 + kbse, 128);
                #pragma unroll
                for (int mt = 0; mt < 3; ++mt) {
                    bf16x8 a = ldfrag(Pb, mt * 16 + lr, ks * 64 + kbse, 128);
                    oacc[mt] = mfma16(a, b, oacc[mt]);
                }
            }
            int col = h * 64 + wid * 16 + lr;
            #pragma unroll
            for (int mt = 0; mt < 3; ++mt)
                #pragma unroll
                for (int j = 0; j < 4; ++j)
                    stswz(Hb, mt * 16 + lg * 4 + j, col, 256, f2bf(oacc[mt][j]));
        }
        __syncthreads();
    }

    // ================= out proj + residual -> Sf =================
    {
        f32x4 pacc[3][2];
        #pragma unroll
        for (int m = 0; m < 3; ++m) { pacc[m][0] = fzero; pacc[m][1] = fzero; }
        #pragma unroll
        for (int ks = 0; ks < 4; ++ks) {
            bf16x8 a0 = ldfrag(Hb,      lr, ks * 64 + kbse, 256);
            bf16x8 a1 = ldfrag(Hb, 16 + lr, ks * 64 + kbse, 256);
            bf16x8 a2 = ldfrag(Hb, 32 + lr, ks * 64 + kbse, 256);
            #pragma unroll
            for (int t = 0; t < 2; ++t) {
                bf16x8 b = ldfragG(opwb, (wid * 2 + t) * 16 + lr, ks * 64 + kbse, 256);
                pacc[0][t] = mfma16(a0, b, pacc[0][t]);
                pacc[1][t] = mfma16(a1, b, pacc[1][t]);
                pacc[2][t] = mfma16(a2, b, pacc[2][t]);
            }
        }
        #pragma unroll
        for (int t = 0; t < 2; ++t) {
            int col = (wid * 2 + t) * 16 + lr;
            float bias = opb[col];
            #pragma unroll
            for (int mt = 0; mt < 3; ++mt)
                #pragma unroll
                for (int j = 0; j < 4; ++j) {
                    int r = mt * 16 + lg * 4 + j;
                    if (r < 36) Sf[r * 129 + col] += pacc[mt][t][j] + bias;
                }
        }
    }
    __syncthreads();

    // ---- LN1: 4 lanes per row; writes Sf (fp32) + Sb (bf16) ----
    {
        int g = tid >> 2, e = tid & 3;
        if (g < 36) {
            float vals[32];
            float sum = 0.f, sq = 0.f;
            #pragma unroll
            for (int i = 0; i < 32; ++i) {
                float v = Sf[g * 129 + e + 4 * i];
                vals[i] = v; sum += v; sq += v * v;
            }
            sum += __shfl_xor(sum, 1); sum += __shfl_xor(sum, 2);
            sq  += __shfl_xor(sq, 1);  sq  += __shfl_xor(sq, 2);
            float m = sum * (1.f / 128.f);
            float rstd = rsqrtf(sq * (1.f / 128.f) - m * m + EPSV);
            #pragma unroll
            for (int i = 0; i < 32; ++i) {
                int c = e + 4 * i;
                float v = (vals[i] - m) * rstd * l1g[c] + l1b[c];
                Sf[g * 129 + c] = v;
                stswz(Sb, g, c, 256, f2bf(v));
            }
        }
    }
    __syncthreads();

    // ================= FFN: per-wave chunks, zero barriers =================
    f32x4 facc[3][8];
    #pragma unroll
    for (int m = 0; m < 3; ++m)
        #pragma unroll
        for (int n = 0; n < 8; ++n) facc[m][n] = fzero;

    const int myn0 = wid * 512;              // this wave's first neuron
    #pragma unroll 2
    for (int q = 0; q < 8; ++q) {            // 8 half-chunks of 64 neurons
        const int nbase = myn0 + q * 64;
        // FFN1: 64 neurons
        f32x4 hacc[3][4];
        #pragma unroll
        for (int m = 0; m < 3; ++m)
            #pragma unroll
            for (int n = 0; n < 4; ++n) hacc[m][n] = fzero;
        #pragma unroll
        for (int ks = 0; ks < 4; ++ks) {
            bf16x8 a0 = ldfrag(Sb,      lr, ks * 64 + kbse, 256);
            bf16x8 a1 = ldfrag(Sb, 16 + lr, ks * 64 + kbse, 256);
            bf16x8 a2 = ldfrag(Sb, 32 + lr, ks * 64 + kbse, 256);
            #pragma unroll
            for (int nt = 0; nt < 4; ++nt) {
                bf16x8 b = ldfragG(fw1b, nbase + nt * 16 + lr, ks * 64 + kbse, 256);
                hacc[0][nt] = mfma16(a0, b, hacc[0][nt]);
                hacc[1][nt] = mfma16(a1, b, hacc[1][nt]);
                hacc[2][nt] = mfma16(a2, b, hacc[2][nt]);
            }
        }
        // stage relu(H) to per-wave scratch (same-wave dependency only)
        #pragma unroll
        for (int nt = 0; nt < 4; ++nt) {
            int coln = nt * 16 + lr;
            float bias = fb1[nbase + coln];
            #pragma unroll
            for (int mt = 0; mt < 3; ++mt)
                #pragma unroll
                for (int j = 0; j < 4; ++j)
                    stswz(scr, mt * 16 + lg * 4 + j, coln, 128,
                          f2bf(fmaxf(hacc[mt][nt][j] + bias, 0.f)));
        }
        // FFN2: consume the 64 neurons
        #pragma unroll
        for (int ks = 0; ks < 2; ++ks) {
            bf16x8 a0 = ldfrag(scr,      lr, ks * 64 + kbse, 128);
            bf16x8 a1 = ldfrag(scr, 16 + lr, ks * 64 + kbse, 128);
            bf16x8 a2 = ldfrag(scr, 32 + lr, ks * 64 + kbse, 128);
            #pragma unroll
            for (int nt = 0; nt < 8; ++nt) {
                bf16x8 b = ldfragG(fw2b, nt * 16 + lr, nbase * 2 + ks * 64 + kbse, 4096);
                facc[0][nt] = mfma16(a0, b, facc[0][nt]);
                facc[1][nt] = mfma16(a1, b, facc[1][nt]);
                facc[2][nt] = mfma16(a2, b, facc[2][nt]);
            }
        }
    }

    // ---- reduce partial O into Sf (rotating disjoint 32-col blocks) ----
    for (int rr = 0; rr < 4; ++rr) {
        if (rr) __syncthreads();
        int u = (wid + rr) & 3;
        #pragma unroll
        for (int nn = 0; nn < 2; ++nn) {
            int nt = u * 2 + nn;
            int col = nt * 16 + lr;
            float bias = (rr == 0) ? fb2[col] : 0.f;
            #pragma unroll
            for (int mt = 0; mt < 3; ++mt)
                #pragma unroll
                for (int j = 0; j < 4; ++j) {
                    int r = mt * 16 + lg * 4 + j;
                    if (r < 36) Sf[r * 129 + col] += facc[mt][nt][j] + bias;
                }
        }
    }
    __syncthreads();

    // ---- LN2 -> Sf ----
    {
        int g = tid >> 2, e = tid & 3;
        if (g < 36) {
            float vals[32];
            float sum = 0.f, sq = 0.f;
            #pragma unroll
            for (int i = 0; i < 32; ++i) {
                float v = Sf[g * 129 + e + 4 * i];
                vals[i] = v; sum += v; sq += v * v;
            }
            sum += __shfl_xor(sum, 1); sum += __shfl_xor(sum, 2);
            sq  += __shfl_xor(sq, 1);  sq  += __shfl_xor(sq, 2);
            float m = sum * (1.f / 128.f);
            float rstd = rsqrtf(sq * (1.f / 128.f) - m * m + EPSV);
            #pragma unroll
            for (int i = 0; i < 32; ++i) {
                int c = e + 4 * i;
                Sf[g * 129 + c] = (vals[i] - m) * rstd * l2g[c] + l2b[c];
            }
        }
    }
    __syncthreads();
    for (int idx = tid; idx < 4608; idx += 256) {
        int r = idx >> 7, c = idx & 127;
        sg[idx] = Sf[r * 129 + c];
    }
}

// ---------------------------------------------------------------------------
// pool + head (unchanged)
// ---------------------------------------------------------------------------
__global__ __launch_bounds__(128) void pool_head(
    const float* __restrict__ sbuf, const float* __restrict__ xgcn,
    const float* __restrict__ aww, const float* __restrict__ awb,
    const float* __restrict__ fcw, const float* __restrict__ fcb,
    float* __restrict__ out)
{
    __shared__ float sl[36][128];
    __shared__ float z[36];
    __shared__ float p[128];
    int tid = threadIdx.x;
    int b = blockIdx.x;
    const float* sg = sbuf + (size_t)b * 4608;
    const float* gg = xgcn + (size_t)b * 4608;
    for (int idx = tid; idx < 4608; idx += 128)
        sl[0][idx] = sg[idx] + gg[idx];
    __syncthreads();
    if (tid < 36) {
        float acc = awb[0];
        #pragma unroll
        for (int j = 0; j < 128; j += 4) {
            float4 s4 = *(const float4*)&sl[tid][j];
            float4 w4 = *(const float4*)(aww + j);
            acc += s4.x * w4.x + s4.y * w4.y + s4.z * w4.z + s4.w * w4.w;
        }
        z[tid] = acc;
    }
    __syncthreads();
    if (tid == 0) {
        float m = -1e30f;
        for (int k = 0; k < 36; ++k) m = fmaxf(m, z[k]);
        float ssum = 0.f;
        for (int k = 0; k < 36; ++k) ssum += __expf(z[k] - m);
        float inv = 1.f / ssum;
        for (int k = 0; k < 36; ++k) z[k] = __expf(z[k] - m) * inv;
    }
    __syncthreads();
    {
        float acc = 0.f;
        for (int l = 0; l < 36; ++l) acc += sl[l][tid] * z[l];
        p[tid] = acc;
    }
    __syncthreads();
    if (tid == 0) {
        float acc = fcb[0];
        for (int dd = 0; dd < 128; ++dd) acc += p[dd] * fcw[dd];
        out[b] = acc >= 0.f ? acc : 0.1f * acc;
    }
}

// ---------------------------------------------------------------------------
extern "C" void kernel_launch(void* const* d_in, const int* in_sizes, int n_in,
                              void* d_out, int out_size, void* d_ws, size_t ws_size,
                              hipStream_t stream)
{
    const float* x   = (const float*)d_in[0];
    const float* Wg1 = (const float*)d_in[1];
    const float* bg1 = (const float*)d_in[2];
    const float* Wg2 = (const float*)d_in[3];
    const float* bg2 = (const float*)d_in[4];
    const float* c1w = (const float*)d_in[5];
    const float* c1b = (const float*)d_in[6];
    const float* c2w = (const float*)d_in[7];
    const float* c2b = (const float*)d_in[8];
    const float* bng = (const float*)d_in[9];
    const float* bnb = (const float*)d_in[10];
    const float* bnm = (const float*)d_in[11];
    const float* bnv = (const float*)d_in[12];
    const float* ipw = (const float*)d_in[13];
    const float* ipb = (const float*)d_in[14];
    const float* opw = (const float*)d_in[15];
    const float* opb = (const float*)d_in[16];
    const float* l1g = (const float*)d_in[17];
    const float* l1b = (const float*)d_in[18];
    const float* l2g = (const float*)d_in[19];
    const float* l2b = (const float*)d_in[20];
    const float* fw1 = (const float*)d_in[21];
    const float* fb1 = (const float*)d_in[22];
    const float* fw2 = (const float*)d_in[23];
    const float* fb2 = (const float*)d_in[24];
    const float* aww = (const float*)d_in[25];
    const float* awb = (const float*)d_in[26];
    const float* fcw = (const float*)d_in[27];
    const float* fcb = (const float*)d_in[28];
    float* out = (float*)d_out;

    float* sbuf = (float*)d_ws;                       // 1024*36*128 f32
    float* xgcn = sbuf + (size_t)1024 * 36 * 128;     // 1024*36*128 f32
    short* wb   = (short*)(xgcn + (size_t)1024 * 36 * 128);
    short* ipwb = wb;                  // 2*384*128
    short* opwb = wb + 98304;          // 2*128*128
    short* fw1b = wb + 131072;         // 2*2048*128
    short* fw2b = wb + 655360;         // 2*128*2048

    cvt_bf16<<<96,  256, 0, stream>>>(ipw, ipwb, 98304);
    cvt_bf16<<<32,  256, 0, stream>>>(opw, opwb, 32768);
    cvt_bf16<<<512, 256, 0, stream>>>(fw1, fw1b, 524288);
    cvt_bf16<<<512, 256, 0, stream>>>(fw2, fw2b, 524288);

    gcn_main<<<18432, 256, 0, stream>>>(x, Wg1, bg1, Wg2, bg2, xgcn);
    gcn_small<<<1, 128, 0, stream>>>(x, Wg1, bg1, Wg2, bg2, xgcn);
    conv_branch<<<1024, 256, 0, stream>>>(x, c1w, c1b, c2w, c2b,
                                          bng, bnb, bnm, bnv, sbuf);
    for (int i = 0; i < 2; ++i) {
        xformer_mfma<<<1024, 256, 0, stream>>>(sbuf,
            ipwb + (size_t)i * 49152, ipb + (size_t)i * 384,
            opwb + (size_t)i * 16384, opb + (size_t)i * 128,
            l1g + (size_t)i * 128, l1b + (size_t)i * 128,
            l2g + (size_t)i * 128, l2b + (size_t)i * 128,
            fw1b + (size_t)i * 262144, fb1 + (size_t)i * 2048,
            fw2b + (size_t)i * 262144, fb2 + (size_t)i * 128);
    }
    pool_head<<<1024, 128, 0, stream>>>(sbuf, xgcn, aww, awb, fcw, fcb, out);
}

// Round 4
// 417.823 us; speedup vs baseline: 1.7834x; 1.7834x over previous
//
#include <hip/hip_runtime.h>
#include <math.h>

#define EPSV   1e-5f

typedef __attribute__((ext_vector_type(8))) short bf16x8;
typedef __attribute__((ext_vector_type(4))) float f32x4;

__device__ __forceinline__ short f2bf(float f){
    unsigned u = __float_as_uint(f);
    u += 0x7fffu + ((u >> 16) & 1u);
    return (short)(u >> 16);
}
__device__ __forceinline__ f32x4 mfma16(bf16x8 a, bf16x8 b, f32x4 c){
    return __builtin_amdgcn_mfma_f32_16x16x32_bf16(a, b, c, 0, 0, 0);
}
__device__ __forceinline__ bf16x8 ldfrag(const short* base, int row, int kbyte, int rowBytes){
    int byte = row * rowBytes + kbyte;
    byte ^= (row & 7) << 4;
    return *(const bf16x8*)((const char*)base + byte);
}
__device__ __forceinline__ bf16x8 ldfragG(const short* base, int row, int kbyte, int rowBytes){
    return *(const bf16x8*)((const char*)base + (size_t)row * rowBytes + kbyte);
}
__device__ __forceinline__ void stswz(short* base, int row, int col, int rowBytes, short v){
    int byte = row * rowBytes + col * 2;
    byte ^= (row & 7) << 4;
    *(short*)((char*)base + byte) = v;
}

// ---------------------------------------------------------------------------
__global__ __launch_bounds__(256) void cvt_bf16(const float* __restrict__ src,
                                                short* __restrict__ dst, int n)
{
    int i = (blockIdx.x * 256 + threadIdx.x) * 4;
    if (i + 3 < n) {
        float4 v = *(const float4*)(src + i);
        short4 s;
        s.x = f2bf(v.x); s.y = f2bf(v.y); s.z = f2bf(v.z); s.w = f2bf(v.w);
        *(short4*)(dst + i) = s;
    }
}

// ---------------------------------------------------------------------------
// GCN branch
// ---------------------------------------------------------------------------
__global__ __launch_bounds__(256) void gcn_main(
    const float* __restrict__ x,
    const float* __restrict__ Wg1, const float* __restrict__ bg1,
    const float* __restrict__ Wg2, const float* __restrict__ bg2,
    float* __restrict__ xgcn)
{
    __shared__ float xg[2][9];
    __shared__ float h1[2][64];
    int tid = threadIdx.x;
    int ri = tid >> 7;
    int tr = tid & 127;
    int row = blockIdx.x * 2 + ri;

    if (tr < 9) {
        const float* xp = x + (row * 9 + tr) * 7;
        float s = 0.f;
        #pragma unroll
        for (int f = 0; f < 7; ++f) s += xp[f];
        xg[ri][tr] = s * (1.f / 7.f);
    }
    __syncthreads();
    if (tr < 64) {
        float acc = bg1[tr];
        #pragma unroll
        for (int j = 0; j < 9; ++j) acc += xg[ri][j] * Wg1[j * 64 + tr];
        h1[ri][tr] = fmaxf(acc, 0.f);
    }
    __syncthreads();
    {
        float acc = bg2[tr];
        #pragma unroll 8
        for (int c = 0; c < 64; ++c) acc += h1[ri][c] * Wg2[c * 128 + tr];
        xgcn[row * 128 + tr] = fmaxf(acc, 0.f);
    }
}

__global__ void gcn_small(
    const float* __restrict__ x,
    const float* __restrict__ Wg1, const float* __restrict__ bg1,
    const float* __restrict__ Wg2, const float* __restrict__ bg2,
    float* __restrict__ xgcn)
{
    __shared__ float xgm[9];
    __shared__ float h1[64];
    int tid = threadIdx.x;
    if (tid < 9) {
        float s = 0.f;
        for (int r = 0; r < 9; ++r) {
            const float* xp = x + (r * 9 + tid) * 7;
            #pragma unroll
            for (int f = 0; f < 7; ++f) s += xp[f];
        }
        xgm[tid] = s * (1.f / 63.f);
    }
    __syncthreads();
    if (tid < 64) {
        float acc = bg1[tid];
        #pragma unroll
        for (int j = 0; j < 9; ++j) acc += xgm[j] * Wg1[j * 64 + tid];
        h1[tid] = fmaxf(acc, 0.f);
    }
    __syncthreads();
    {
        float acc = bg2[tid];
        #pragma unroll 8
        for (int c = 0; c < 64; ++c) acc += h1[c] * Wg2[c * 128 + tid];
        float v = fmaxf(acc, 0.f);
        for (int r = 0; r < 9; ++r) xgcn[r * 128 + tid] = v;
    }
}

// ---------------------------------------------------------------------------
// Conv branch
// ---------------------------------------------------------------------------
__global__ __launch_bounds__(256) void conv_branch(
    const float* __restrict__ x,
    const float* __restrict__ w1, const float* __restrict__ cb1,
    const float* __restrict__ w2, const float* __restrict__ cb2,
    const float* __restrict__ bng, const float* __restrict__ bnb,
    const float* __restrict__ bnm, const float* __restrict__ bnv,
    float* __restrict__ sbuf)
{
    __shared__ float xm[7 * 40];
    __shared__ float w1s[64 * 35];
    __shared__ float o1[64 * 38];
    int tid = threadIdx.x;
    int b = blockIdx.x;

    for (int idx = tid; idx < 7 * 40; idx += 256) xm[idx] = 0.f;
    for (int idx = tid; idx < 64 * 38; idx += 256) o1[idx] = 0.f;
    for (int idx = tid; idx < 2240; idx += 256) w1s[idx] = w1[idx];
    __syncthreads();

    const float* xb = x + (size_t)b * 2268;
    for (int idx = tid; idx < 252; idx += 256) {
        int f = idx / 36, l = idx - f * 36;
        float s = 0.f;
        #pragma unroll
        for (int n = 0; n < 9; ++n) s += xb[n * 252 + idx];
        xm[f * 40 + l + 2] = s * (1.f / 9.f);
    }
    __syncthreads();

    {
        int o = tid & 63, lh = tid >> 6;
        int l0 = lh * 9;
        float acc[9];
        float bias = cb1[o];
        #pragma unroll
        for (int r = 0; r < 9; ++r) acc[r] = bias;
        #pragma unroll
        for (int i = 0; i < 7; ++i) {
            #pragma unroll
            for (int k = 0; k < 5; ++k) {
                float w = w1s[o * 35 + i * 5 + k];
                const float* xrow = &xm[i * 40 + l0 + k];
                #pragma unroll
                for (int r = 0; r < 9; ++r) acc[r] += w * xrow[r];
            }
        }
        #pragma unroll
        for (int r = 0; r < 9; ++r) o1[o * 38 + l0 + r + 1] = acc[r];
    }
    __syncthreads();

    {
        int c = tid & 127, lh = tid >> 7;
        int l0 = lh * 18;
        float acc[18];
        #pragma unroll
        for (int r = 0; r < 18; ++r) acc[r] = 0.f;
        const float* w2c = w2 + c * 192;
        for (int i = 0; i < 64; ++i) {
            float wa = w2c[i * 3 + 0], wb = w2c[i * 3 + 1], wc = w2c[i * 3 + 2];
            const float* orow = &o1[i * 38 + l0];
            #pragma unroll
            for (int r = 0; r < 18; ++r)
                acc[r] += wa * orow[r] + wb * orow[r + 1] + wc * orow[r + 2];
        }
        float scale = bng[c] * rsqrtf(bnv[c] + EPSV);
        float shift = bnb[c] - bnm[c] * scale;
        float bias  = cb2[c];
        float* sb = sbuf + ((size_t)b * 36 + l0) * 128 + c;
        #pragma unroll
        for (int r = 0; r < 18; ++r)
            sb[r * 128] = (acc[r] + bias) * scale + shift;
    }
}

// ---------------------------------------------------------------------------
// Fused transformer layer v3: cooperative FFN (low reg pressure) with
// ping-pong H buffer (1 barrier/chunk) + weight prefetch into registers.
// ---------------------------------------------------------------------------
__global__ __launch_bounds__(256, 2) void xformer_mfma(
    float* __restrict__ sbuf,
    const short* __restrict__ ipwb, const float* __restrict__ ipb,
    const short* __restrict__ opwb, const float* __restrict__ opb,
    const float* __restrict__ l1g, const float* __restrict__ l1b,
    const float* __restrict__ l2g, const float* __restrict__ l2b,
    const short* __restrict__ fw1b, const float* __restrict__ fb1,
    const short* __restrict__ fw2b, const float* __restrict__ fb2)
{
    __shared__ float Sf[36 * 129];                               // 18576 B
    __shared__ short Sb[48 * 128] __attribute__((aligned(16)));  // 12288 B
    __shared__ char  U[38912]     __attribute__((aligned(16)));  // union
    __shared__ float scf[36 * 40];                               // 5760 B
    // attention views of U:
    short* Qb = (short*)U;               // 48x64   (6144)
    short* Kb = (short*)(U + 6144);      // 48x64   (6144)
    short* Vt = (short*)(U + 12288);     // 64x64   (8192)  [d][seq]
    short* Pb = (short*)(U + 20480);     // 48x64   (6144)
    short* Hb = (short*)(U + 26624);     // 48x128  (12288)
    // FFN ping-pong views of U (attention data dead by then):
    short* pingA = (short*)U;            // 48x128  (12288)
    short* pingB = (short*)(U + 12288);  // 48x128  (12288)

    const int tid  = threadIdx.x;
    const int wid  = tid >> 6;
    const int lane = tid & 63;
    const int lr   = lane & 15;
    const int lg   = lane >> 4;
    const int kbse = lg * 16;

    float* sg = sbuf + (size_t)blockIdx.x * 4608;
    const f32x4 fzero = {0.f, 0.f, 0.f, 0.f};

    // ---- init ----
    for (int idx = tid; idx < 4608; idx += 256) {
        int r = idx >> 7, c = idx & 127;
        float v = sg[idx];
        Sf[r * 129 + c] = v;
        stswz(Sb, r, c, 256, f2bf(v));
    }
    for (int idx = tid; idx < 1536; idx += 256)
        stswz(Sb, 36 + (idx >> 7), idx & 127, 256, 0);
    for (int idx = tid; idx < 1024; idx += 256)
        stswz(Vt, idx >> 4, 48 + (idx & 15), 128, 0);
    for (int idx = tid; idx < 768; idx += 256)
        stswz(Pb, 36 + (idx >> 6), idx & 63, 128, 0);
    __syncthreads();

    // ================= attention =================
    for (int h = 0; h < 2; ++h) {
        {   // q,k,v projections
            f32x4 acc[3][3];
            #pragma unroll
            for (int a = 0; a < 3; ++a)
                #pragma unroll
                for (int m = 0; m < 3; ++m) acc[a][m] = fzero;
            const int wrow0 = h * 64 + wid * 16 + lr;
            #pragma unroll
            for (int ks = 0; ks < 4; ++ks) {
                bf16x8 a0 = ldfrag(Sb,      lr, ks * 64 + kbse, 256);
                bf16x8 a1 = ldfrag(Sb, 16 + lr, ks * 64 + kbse, 256);
                bf16x8 a2 = ldfrag(Sb, 32 + lr, ks * 64 + kbse, 256);
                #pragma unroll
                for (int mat = 0; mat < 3; ++mat) {
                    bf16x8 bf = ldfragG(ipwb, mat * 128 + wrow0, ks * 64 + kbse, 256);
                    acc[mat][0] = mfma16(a0, bf, acc[mat][0]);
                    acc[mat][1] = mfma16(a1, bf, acc[mat][1]);
                    acc[mat][2] = mfma16(a2, bf, acc[mat][2]);
                }
            }
            int col = wid * 16 + lr;
            #pragma unroll
            for (int mat = 0; mat < 3; ++mat) {
                float bias = ipb[mat * 128 + h * 64 + col];
                #pragma unroll
                for (int mt = 0; mt < 3; ++mt) {
                    f32x4 c4 = acc[mat][mt];
                    if (mat == 0) {
                        #pragma unroll
                        for (int j = 0; j < 4; ++j)
                            stswz(Qb, mt * 16 + lg * 4 + j, col, 128, f2bf(c4[j] + bias));
                    } else if (mat == 1) {
                        #pragma unroll
                        for (int j = 0; j < 4; ++j)
                            stswz(Kb, mt * 16 + lg * 4 + j, col, 128, f2bf(c4[j] + bias));
                    } else {
                        short4 s4;
                        s4.x = f2bf(c4[0] + bias); s4.y = f2bf(c4[1] + bias);
                        s4.z = f2bf(c4[2] + bias); s4.w = f2bf(c4[3] + bias);
                        int byte = col * 128 + (mt * 16 + lg * 4) * 2;
                        byte ^= (col & 7) << 4;
                        *(short4*)((char*)Vt + byte) = s4;
                    }
                }
            }
        }
        __syncthreads();

        // ---- scores ----
        for (int t = wid; t < 9; t += 4) {
            int mt = t / 3, nt = t - mt * 3;
            f32x4 acc = fzero;
            #pragma unroll
            for (int ks = 0; ks < 2; ++ks) {
                bf16x8 a = ldfrag(Qb, mt * 16 + lr, ks * 64 + kbse, 128);
                bf16x8 b = ldfrag(Kb, nt * 16 + lr, ks * 64 + kbse, 128);
                acc = mfma16(a, b, acc);
            }
            int col = nt * 16 + lr;
            if (col < 36) {
                #pragma unroll
                for (int j = 0; j < 4; ++j) {
                    int r = mt * 16 + lg * 4 + j;
                    if (r < 36) scf[r * 40 + col] = acc[j] * 0.125f;
                }
            }
        }
        __syncthreads();

        // ---- softmax: 4 lanes per row ----
        {
            int g = tid >> 2, e = tid & 3;
            if (g < 36) {
                float v[9];
                float mx = -1e30f;
                #pragma unroll
                for (int i = 0; i < 9; ++i) { v[i] = scf[g * 40 + e * 9 + i]; mx = fmaxf(mx, v[i]); }
                mx = fmaxf(mx, __shfl_xor(mx, 1));
                mx = fmaxf(mx, __shfl_xor(mx, 2));
                float ssum = 0.f;
                #pragma unroll
                for (int i = 0; i < 9; ++i) { v[i] = __expf(v[i] - mx); ssum += v[i]; }
                ssum += __shfl_xor(ssum, 1);
                ssum += __shfl_xor(ssum, 2);
                float inv = 1.f / ssum;
                #pragma unroll
                for (int i = 0; i < 9; ++i)
                    stswz(Pb, g, e * 9 + i, 128, f2bf(v[i] * inv));
                #pragma unroll
                for (int i = 0; i < 7; ++i)
                    stswz(Pb, g, 36 + e * 7 + i, 128, 0);
            }
        }
        __syncthreads();

        // ---- o = P @ V ----
        {
            f32x4 oacc[3] = {fzero, fzero, fzero};
            #pragma unroll
            for (int ks = 0; ks < 2; ++ks) {
                bf16x8 b = ldfrag(Vt, wid * 16 + lr, ks * 64 + kbse, 128);
                #pragma unroll
                for (int mt = 0; mt < 3; ++mt) {
                    bf16x8 a = ldfrag(Pb, mt * 16 + lr, ks * 64 + kbse, 128);
                    oacc[mt] = mfma16(a, b, oacc[mt]);
                }
            }
            int col = h * 64 + wid * 16 + lr;
            #pragma unroll
            for (int mt = 0; mt < 3; ++mt)
                #pragma unroll
                for (int j = 0; j < 4; ++j)
                    stswz(Hb, mt * 16 + lg * 4 + j, col, 256, f2bf(oacc[mt][j]));
        }
        __syncthreads();
    }

    // ================= out proj + residual -> Sf =================
    {
        f32x4 pacc[3][2];
        #pragma unroll
        for (int m = 0; m < 3; ++m) { pacc[m][0] = fzero; pacc[m][1] = fzero; }
        #pragma unroll
        for (int ks = 0; ks < 4; ++ks) {
            bf16x8 a0 = ldfrag(Hb,      lr, ks * 64 + kbse, 256);
            bf16x8 a1 = ldfrag(Hb, 16 + lr, ks * 64 + kbse, 256);
            bf16x8 a2 = ldfrag(Hb, 32 + lr, ks * 64 + kbse, 256);
            #pragma unroll
            for (int t = 0; t < 2; ++t) {
                bf16x8 b = ldfragG(opwb, (wid * 2 + t) * 16 + lr, ks * 64 + kbse, 256);
                pacc[0][t] = mfma16(a0, b, pacc[0][t]);
                pacc[1][t] = mfma16(a1, b, pacc[1][t]);
                pacc[2][t] = mfma16(a2, b, pacc[2][t]);
            }
        }
        #pragma unroll
        for (int t = 0; t < 2; ++t) {
            int col = (wid * 2 + t) * 16 + lr;
            float bias = opb[col];
            #pragma unroll
            for (int mt = 0; mt < 3; ++mt)
                #pragma unroll
                for (int j = 0; j < 4; ++j) {
                    int r = mt * 16 + lg * 4 + j;
                    if (r < 36) Sf[r * 129 + col] += pacc[mt][t][j] + bias;
                }
        }
    }
    __syncthreads();

    // ---- LN1: 4 lanes per row; writes Sf (fp32) + Sb (bf16) ----
    {
        int g = tid >> 2, e = tid & 3;
        if (g < 36) {
            float vals[32];
            float sum = 0.f, sq = 0.f;
            #pragma unroll
            for (int i = 0; i < 32; ++i) {
                float v = Sf[g * 129 + e + 4 * i];
                vals[i] = v; sum += v; sq += v * v;
            }
            sum += __shfl_xor(sum, 1); sum += __shfl_xor(sum, 2);
            sq  += __shfl_xor(sq, 1);  sq  += __shfl_xor(sq, 2);
            float m = sum * (1.f / 128.f);
            float rstd = rsqrtf(sq * (1.f / 128.f) - m * m + EPSV);
            #pragma unroll
            for (int i = 0; i < 32; ++i) {
                int c = e + 4 * i;
                float v = (vals[i] - m) * rstd * l1g[c] + l1b[c];
                Sf[g * 129 + c] = v;
                stswz(Sb, g, c, 256, f2bf(v));
            }
        }
    }
    __syncthreads();

    // ================= FFN: cooperative chunks, ping-pong, prefetch ========
    // Per chunk (128 neurons): FFN1 -> relu -> H buf[q&1]; 1 barrier; FFN2.
    // fw2 frags prefetched at chunk start (hidden under FFN1 MFMAs);
    // fw1 frags for q+1 prefetched right after the barrier (hidden under FFN2).
    bf16x8 sa[3][4];
    #pragma unroll
    for (int mt = 0; mt < 3; ++mt)
        #pragma unroll
        for (int ks = 0; ks < 4; ++ks)
            sa[mt][ks] = ldfrag(Sb, mt * 16 + lr, ks * 64 + kbse, 256);

    bf16x8 p1[8], p2[8];
    f32x4 facc[3][2];
    #pragma unroll
    for (int m = 0; m < 3; ++m) { facc[m][0] = fzero; facc[m][1] = fzero; }

    // prologue: prefetch fw1 chunk 0
    #pragma unroll
    for (int t = 0; t < 2; ++t)
        #pragma unroll
        for (int ks = 0; ks < 4; ++ks)
            p1[t * 4 + ks] = ldfragG(fw1b, (wid * 2 + t) * 16 + lr, ks * 64 + kbse, 256);

#define FFN_CHUNK(Q, BUF)                                                         \
    {                                                                             \
        const int q = (Q);                                                        \
        /* prefetch fw2 for this chunk + fb1 biases */                            \
        _Pragma("unroll")                                                         \
        for (int t = 0; t < 2; ++t)                                               \
            _Pragma("unroll")                                                     \
            for (int ks = 0; ks < 4; ++ks)                                        \
                p2[t * 4 + ks] = ldfragG(fw2b, (wid * 2 + t) * 16 + lr,           \
                                         q * 256 + ks * 64 + kbse, 4096);         \
        float b1_0 = fb1[q * 128 + wid * 32 + lr];                                \
        float b1_1 = fb1[q * 128 + wid * 32 + 16 + lr];                           \
        /* FFN1 */                                                                \
        f32x4 hacc[3][2];                                                         \
        _Pragma("unroll")                                                         \
        for (int m = 0; m < 3; ++m) { hacc[m][0] = fzero; hacc[m][1] = fzero; }   \
        _Pragma("unroll")                                                         \
        for (int ks = 0; ks < 4; ++ks)                                            \
            _Pragma("unroll")                                                     \
            for (int t = 0; t < 2; ++t) {                                         \
                hacc[0][t] = mfma16(sa[0][ks], p1[t * 4 + ks], hacc[0][t]);       \
                hacc[1][t] = mfma16(sa[1][ks], p1[t * 4 + ks], hacc[1][t]);       \
                hacc[2][t] = mfma16(sa[2][ks], p1[t * 4 + ks], hacc[2][t]);       \
            }                                                                     \
        /* relu + stage H */                                                      \
        _Pragma("unroll")                                                         \
        for (int t = 0; t < 2; ++t) {                                             \
            int coln = (wid * 2 + t) * 16 + lr;                                   \
            float bias = t ? b1_1 : b1_0;                                         \
            _Pragma("unroll")                                                     \
            for (int mt = 0; mt < 3; ++mt)                                        \
                _Pragma("unroll")                                                 \
                for (int j = 0; j < 4; ++j)                                       \
                    stswz(BUF, mt * 16 + lg * 4 + j, coln, 256,                   \
                          f2bf(fmaxf(hacc[mt][t][j] + bias, 0.f)));               \
        }                                                                         \
        __syncthreads();                                                          \
        /* prefetch fw1 for next chunk */                                         \
        if (q < 15) {                                                             \
            _Pragma("unroll")                                                     \
            for (int t = 0; t < 2; ++t)                                           \
                _Pragma("unroll")                                                 \
                for (int ks = 0; ks < 4; ++ks)                                    \
                    p1[t * 4 + ks] = ldfragG(fw1b,                                \
                        (q + 1) * 128 + (wid * 2 + t) * 16 + lr,                  \
                        ks * 64 + kbse, 256);                                     \
        }                                                                         \
        /* FFN2 */                                                                \
        _Pragma("unroll")                                                         \
        for (int ks = 0; ks < 4; ++ks) {                                          \
            bf16x8 a0 = ldfrag(BUF,      lr, ks * 64 + kbse, 256);                \
            bf16x8 a1 = ldfrag(BUF, 16 + lr, ks * 64 + kbse, 256);                \
            bf16x8 a2 = ldfrag(BUF, 32 + lr, ks * 64 + kbse, 256);                \
            _Pragma("unroll")                                                     \
            for (int t = 0; t < 2; ++t) {                                         \
                facc[0][t] = mfma16(a0, p2[t * 4 + ks], facc[0][t]);              \
                facc[1][t] = mfma16(a1, p2[t * 4 + ks], facc[1][t]);              \
                facc[2][t] = mfma16(a2, p2[t * 4 + ks], facc[2][t]);              \
            }                                                                     \
        }                                                                         \
    }

    #pragma unroll 1
    for (int qq = 0; qq < 8; ++qq) {
        FFN_CHUNK(2 * qq,     pingA)
        FFN_CHUNK(2 * qq + 1, pingB)
    }
#undef FFN_CHUNK

    // ---- FFN epilogue: + b2 + residual into Sf ----
    #pragma unroll
    for (int t = 0; t < 2; ++t) {
        int col = (wid * 2 + t) * 16 + lr;
        float bias = fb2[col];
        #pragma unroll
        for (int mt = 0; mt < 3; ++mt)
            #pragma unroll
            for (int j = 0; j < 4; ++j) {
                int r = mt * 16 + lg * 4 + j;
                if (r < 36) Sf[r * 129 + col] += facc[mt][t][j] + bias;
            }
    }
    __syncthreads();

    // ---- LN2 -> Sf ----
    {
        int g = tid >> 2, e = tid & 3;
        if (g < 36) {
            float vals[32];
            float sum = 0.f, sq = 0.f;
            #pragma unroll
            for (int i = 0; i < 32; ++i) {
                float v = Sf[g * 129 + e + 4 * i];
                vals[i] = v; sum += v; sq += v * v;
            }
            sum += __shfl_xor(sum, 1); sum += __shfl_xor(sum, 2);
            sq  += __shfl_xor(sq, 1);  sq  += __shfl_xor(sq, 2);
            float m = sum * (1.f / 128.f);
            float rstd = rsqrtf(sq * (1.f / 128.f) - m * m + EPSV);
            #pragma unroll
            for (int i = 0; i < 32; ++i) {
                int c = e + 4 * i;
                Sf[g * 129 + c] = (vals[i] - m) * rstd * l2g[c] + l2b[c];
            }
        }
    }
    __syncthreads();
    for (int idx = tid; idx < 4608; idx += 256) {
        int r = idx >> 7, c = idx & 127;
        sg[idx] = Sf[r * 129 + c];
    }
}

// ---------------------------------------------------------------------------
// pool + head
// ---------------------------------------------------------------------------
__global__ __launch_bounds__(128) void pool_head(
    const float* __restrict__ sbuf, const float* __restrict__ xgcn,
    const float* __restrict__ aww, const float* __restrict__ awb,
    const float* __restrict__ fcw, const float* __restrict__ fcb,
    float* __restrict__ out)
{
    __shared__ float sl[36][128];
    __shared__ float z[36];
    __shared__ float p[128];
    int tid = threadIdx.x;
    int b = blockIdx.x;
    const float* sg = sbuf + (size_t)b * 4608;
    const float* gg = xgcn + (size_t)b * 4608;
    for (int idx = tid; idx < 4608; idx += 128)
        sl[0][idx] = sg[idx] + gg[idx];
    __syncthreads();
    if (tid < 36) {
        float acc = awb[0];
        #pragma unroll
        for (int j = 0; j < 128; j += 4) {
            float4 s4 = *(const float4*)&sl[tid][j];
            float4 w4 = *(const float4*)(aww + j);
            acc += s4.x * w4.x + s4.y * w4.y + s4.z * w4.z + s4.w * w4.w;
        }
        z[tid] = acc;
    }
    __syncthreads();
    if (tid == 0) {
        float m = -1e30f;
        for (int k = 0; k < 36; ++k) m = fmaxf(m, z[k]);
        float ssum = 0.f;
        for (int k = 0; k < 36; ++k) ssum += __expf(z[k] - m);
        float inv = 1.f / ssum;
        for (int k = 0; k < 36; ++k) z[k] = __expf(z[k] - m) * inv;
    }
    __syncthreads();
    {
        float acc = 0.f;
        for (int l = 0; l < 36; ++l) acc += sl[l][tid] * z[l];
        p[tid] = acc;
    }
    __syncthreads();
    if (tid == 0) {
        float acc = fcb[0];
        for (int dd = 0; dd < 128; ++dd) acc += p[dd] * fcw[dd];
        out[b] = acc >= 0.f ? acc : 0.1f * acc;
    }
}

// ---------------------------------------------------------------------------
extern "C" void kernel_launch(void* const* d_in, const int* in_sizes, int n_in,
                              void* d_out, int out_size, void* d_ws, size_t ws_size,
                              hipStream_t stream)
{
    const float* x   = (const float*)d_in[0];
    const float* Wg1 = (const float*)d_in[1];
    const float* bg1 = (const float*)d_in[2];
    const float* Wg2 = (const float*)d_in[3];
    const float* bg2 = (const float*)d_in[4];
    const float* c1w = (const float*)d_in[5];
    const float* c1b = (const float*)d_in[6];
    const float* c2w = (const float*)d_in[7];
    const float* c2b = (const float*)d_in[8];
    const float* bng = (const float*)d_in[9];
    const float* bnb = (const float*)d_in[10];
    const float* bnm = (const float*)d_in[11];
    const float* bnv = (const float*)d_in[12];
    const float* ipw = (const float*)d_in[13];
    const float* ipb = (const float*)d_in[14];
    const float* opw = (const float*)d_in[15];
    const float* opb = (const float*)d_in[16];
    const float* l1g = (const float*)d_in[17];
    const float* l1b = (const float*)d_in[18];
    const float* l2g = (const float*)d_in[19];
    const float* l2b = (const float*)d_in[20];
    const float* fw1 = (const float*)d_in[21];
    const float* fb1 = (const float*)d_in[22];
    const float* fw2 = (const float*)d_in[23];
    const float* fb2 = (const float*)d_in[24];
    const float* aww = (const float*)d_in[25];
    const float* awb = (const float*)d_in[26];
    const float* fcw = (const float*)d_in[27];
    const float* fcb = (const float*)d_in[28];
    float* out = (float*)d_out;

    float* sbuf = (float*)d_ws;                       // 1024*36*128 f32
    float* xgcn = sbuf + (size_t)1024 * 36 * 128;     // 1024*36*128 f32
    short* wb   = (short*)(xgcn + (size_t)1024 * 36 * 128);
    short* ipwb = wb;                  // 2*384*128
    short* opwb = wb + 98304;          // 2*128*128
    short* fw1b = wb + 131072;         // 2*2048*128
    short* fw2b = wb + 655360;         // 2*128*2048

    cvt_bf16<<<96,  256, 0, stream>>>(ipw, ipwb, 98304);
    cvt_bf16<<<32,  256, 0, stream>>>(opw, opwb, 32768);
    cvt_bf16<<<512, 256, 0, stream>>>(fw1, fw1b, 524288);
    cvt_bf16<<<512, 256, 0, stream>>>(fw2, fw2b, 524288);

    gcn_main<<<18432, 256, 0, stream>>>(x, Wg1, bg1, Wg2, bg2, xgcn);
    gcn_small<<<1, 128, 0, stream>>>(x, Wg1, bg1, Wg2, bg2, xgcn);
    conv_branch<<<1024, 256, 0, stream>>>(x, c1w, c1b, c2w, c2b,
                                          bng, bnb, bnm, bnv, sbuf);
    for (int i = 0; i < 2; ++i) {
        xformer_mfma<<<1024, 256, 0, stream>>>(sbuf,
            ipwb + (size_t)i * 49152, ipb + (size_t)i * 384,
            opwb + (size_t)i * 16384, opb + (size_t)i * 128,
            l1g + (size_t)i * 128, l1b + (size_t)i * 128,
            l2g + (size_t)i * 128, l2b + (size_t)i * 128,
            fw1b + (size_t)i * 262144, fb1 + (size_t)i * 2048,
            fw2b + (size_t)i * 262144, fb2 + (size_t)i * 128);
    }
    pool_head<<<1024, 128, 0, stream>>>(sbuf, xgcn, aww, awb, fcw, fcb, out);
}